// Round 6
// baseline (55.795 us; speedup 1.0000x reference)
//
#include <hip/hip_runtime.h>

// ContrastiveLoss: B=8192 rows, D=4096 fp32. Single kernel.
// One 64-lane wave per row (4 rows/block, grid=2048). Wave computes
// dot/||a||^2/||b||^2 (4x-unrolled float4 loads), lane 0 computes row loss.
// Block sums its 4 row losses in LDS; thread 0 does ONE fire-and-forget
// atomicAdd of partial/B into d_out[0] (zeroed via hipMemsetAsync each call).
// No fence, no counter, no spin -- 2048 atomics hide under the BW-bound phase
// (R4's 380us tail came from 8192 x {threadfence + contended RMW readback}).
//
// target arrives as int32 (JAX x32 default; harness passes integer -> const int*).

#define WAVE 64
#define BLOCK 256
#define WAVES_PER_BLOCK (BLOCK / WAVE)

__global__ __launch_bounds__(BLOCK) void contrastive_fused_atomic(
    const float* __restrict__ o1,
    const float* __restrict__ o2,
    const int* __restrict__ target,
    float* __restrict__ out,
    float invB, int B, int D) {
    const int wv   = threadIdx.x >> 6;      // 0..3
    const int lane = threadIdx.x & 63;
    const int row  = blockIdx.x * WAVES_PER_BLOCK + wv;

    const float4* __restrict__ p1 =
        reinterpret_cast<const float4*>(o1 + (size_t)row * D);
    const float4* __restrict__ p2 =
        reinterpret_cast<const float4*>(o2 + (size_t)row * D);
    const int nvec = D >> 2;                // 1024 for D=4096

    float dot0 = 0.f, dot1 = 0.f, dot2 = 0.f, dot3 = 0.f;
    float s1_0 = 0.f, s1_1 = 0.f, s1_2 = 0.f, s1_3 = 0.f;
    float s2_0 = 0.f, s2_1 = 0.f, s2_2 = 0.f, s2_3 = 0.f;

    for (int base = lane; base < nvec; base += WAVE * 4) {
        float4 a0 = p1[base];
        float4 a1 = p1[base + WAVE];
        float4 a2 = p1[base + WAVE * 2];
        float4 a3 = p1[base + WAVE * 3];
        float4 b0 = p2[base];
        float4 b1 = p2[base + WAVE];
        float4 b2 = p2[base + WAVE * 2];
        float4 b3 = p2[base + WAVE * 3];

        dot0 += a0.x*b0.x + a0.y*b0.y + a0.z*b0.z + a0.w*b0.w;
        s1_0 += a0.x*a0.x + a0.y*a0.y + a0.z*a0.z + a0.w*a0.w;
        s2_0 += b0.x*b0.x + b0.y*b0.y + b0.z*b0.z + b0.w*b0.w;

        dot1 += a1.x*b1.x + a1.y*b1.y + a1.z*b1.z + a1.w*b1.w;
        s1_1 += a1.x*a1.x + a1.y*a1.y + a1.z*a1.z + a1.w*a1.w;
        s2_1 += b1.x*b1.x + b1.y*b1.y + b1.z*b1.z + b1.w*b1.w;

        dot2 += a2.x*b2.x + a2.y*b2.y + a2.z*b2.z + a2.w*b2.w;
        s1_2 += a2.x*a2.x + a2.y*a2.y + a2.z*a2.z + a2.w*a2.w;
        s2_2 += b2.x*b2.x + b2.y*b2.y + b2.z*b2.z + b2.w*b2.w;

        dot3 += a3.x*b3.x + a3.y*b3.y + a3.z*b3.z + a3.w*b3.w;
        s1_3 += a3.x*a3.x + a3.y*a3.y + a3.z*a3.z + a3.w*a3.w;
        s2_3 += b3.x*b3.x + b3.y*b3.y + b3.z*b3.z + b3.w*b3.w;
    }

    float dot = (dot0 + dot1) + (dot2 + dot3);
    float s1  = (s1_0 + s1_1) + (s1_2 + s1_3);
    float s2  = (s2_0 + s2_1) + (s2_2 + s2_3);

    #pragma unroll
    for (int off = 32; off > 0; off >>= 1) {
        dot += __shfl_down(dot, off, WAVE);
        s1  += __shfl_down(s1,  off, WAVE);
        s2  += __shfl_down(s2,  off, WAVE);
    }

    __shared__ float sl[WAVES_PER_BLOCK];
    if (lane == 0) {
        float cosv = dot / (sqrtf(s1) * sqrtf(s2));
        float dist = 0.5f * (1.0f - cosv);
        int t = target[row];
        float loss;
        if (t != 0) {
            loss = 0.5f * dist;
        } else {
            float h = fmaxf(0.0f, 1.0f - sqrtf(dist + 1e-9f));
            loss = 0.5f * h * h;
        }
        sl[wv] = loss;
    }
    __syncthreads();
    if (threadIdx.x == 0) {
        float partial = (sl[0] + sl[1]) + (sl[2] + sl[3]);
        atomicAdd(out, partial * invB);   // fire-and-forget, device scope
    }
}

extern "C" void kernel_launch(void* const* d_in, const int* in_sizes, int n_in,
                              void* d_out, int out_size, void* d_ws, size_t ws_size,
                              hipStream_t stream) {
    const float* o1 = (const float*)d_in[0];
    const float* o2 = (const float*)d_in[1];
    const int* tgt = (const int*)d_in[2];

    const int B = in_sizes[2];            // 8192
    const int D = in_sizes[0] / B;        // 4096

    float* out = (float*)d_out;

    // Zero the accumulator each call (graph-capturable async memset).
    hipMemsetAsync(out, 0, sizeof(float), stream);

    const int grid = (B + WAVES_PER_BLOCK - 1) / WAVES_PER_BLOCK;  // 2048
    contrastive_fused_atomic<<<grid, BLOCK, 0, stream>>>(
        o1, o2, tgt, out, 1.0f / (float)B, B, D);
}

// Round 7
// 47.077 us; speedup vs baseline: 1.1852x; 1.1852x over previous
//
#include <hip/hip_runtime.h>

// ContrastiveLoss: B=8192 rows, D=4096 fp32 features. Two kernels.
// This is the best-measured structure (R5: 47.6 us). Both single-launch
// fusions regressed: last-block fence+counter = +263us serial tail (R4);
// single-address atomicAdd + memset node = +8us (R6). Kernel 1 runs at ~97%
// of the measured 6.29 TB/s device read ceiling (m13); kernel 2 is ~4us of
// dispatch overhead + 8KB read.
//
// Kernel 1: one 64-lane wave per row (4 rows/block, grid=2048), 4x-unrolled
//   float4 loads, wave-shuffle reduction, lane 0 computes row loss; block
//   writes ONE partial (sum of its 4 row losses).
// Kernel 2: single block reduces 2048 partials in fixed order -> mean.
//
// target arrives as int32 (JAX x32 default; harness passes integer -> const int*).

#define WAVE 64
#define BLOCK 256
#define WAVES_PER_BLOCK (BLOCK / WAVE)

__global__ __launch_bounds__(BLOCK) void contrastive_row_loss(
    const float* __restrict__ o1,
    const float* __restrict__ o2,
    const int* __restrict__ target,
    float* __restrict__ block_partial,
    int B, int D) {
    const int wv   = threadIdx.x >> 6;      // 0..3
    const int lane = threadIdx.x & 63;
    const int row  = blockIdx.x * WAVES_PER_BLOCK + wv;

    const float4* __restrict__ p1 =
        reinterpret_cast<const float4*>(o1 + (size_t)row * D);
    const float4* __restrict__ p2 =
        reinterpret_cast<const float4*>(o2 + (size_t)row * D);
    const int nvec = D >> 2;                // 1024 for D=4096

    float dot0 = 0.f, dot1 = 0.f, dot2 = 0.f, dot3 = 0.f;
    float s1_0 = 0.f, s1_1 = 0.f, s1_2 = 0.f, s1_3 = 0.f;
    float s2_0 = 0.f, s2_1 = 0.f, s2_2 = 0.f, s2_3 = 0.f;

    for (int base = lane; base < nvec; base += WAVE * 4) {
        float4 a0 = p1[base];
        float4 a1 = p1[base + WAVE];
        float4 a2 = p1[base + WAVE * 2];
        float4 a3 = p1[base + WAVE * 3];
        float4 b0 = p2[base];
        float4 b1 = p2[base + WAVE];
        float4 b2 = p2[base + WAVE * 2];
        float4 b3 = p2[base + WAVE * 3];

        dot0 += a0.x*b0.x + a0.y*b0.y + a0.z*b0.z + a0.w*b0.w;
        s1_0 += a0.x*a0.x + a0.y*a0.y + a0.z*a0.z + a0.w*a0.w;
        s2_0 += b0.x*b0.x + b0.y*b0.y + b0.z*b0.z + b0.w*b0.w;

        dot1 += a1.x*b1.x + a1.y*b1.y + a1.z*b1.z + a1.w*b1.w;
        s1_1 += a1.x*a1.x + a1.y*a1.y + a1.z*a1.z + a1.w*a1.w;
        s2_1 += b1.x*b1.x + b1.y*b1.y + b1.z*b1.z + b1.w*b1.w;

        dot2 += a2.x*b2.x + a2.y*b2.y + a2.z*b2.z + a2.w*b2.w;
        s1_2 += a2.x*a2.x + a2.y*a2.y + a2.z*a2.z + a2.w*a2.w;
        s2_2 += b2.x*b2.x + b2.y*b2.y + b2.z*b2.z + b2.w*b2.w;

        dot3 += a3.x*b3.x + a3.y*b3.y + a3.z*b3.z + a3.w*b3.w;
        s1_3 += a3.x*a3.x + a3.y*a3.y + a3.z*a3.z + a3.w*a3.w;
        s2_3 += b3.x*b3.x + b3.y*b3.y + b3.z*b3.z + b3.w*b3.w;
    }

    float dot = (dot0 + dot1) + (dot2 + dot3);
    float s1  = (s1_0 + s1_1) + (s1_2 + s1_3);
    float s2  = (s2_0 + s2_1) + (s2_2 + s2_3);

    #pragma unroll
    for (int off = 32; off > 0; off >>= 1) {
        dot += __shfl_down(dot, off, WAVE);
        s1  += __shfl_down(s1,  off, WAVE);
        s2  += __shfl_down(s2,  off, WAVE);
    }

    __shared__ float sl[WAVES_PER_BLOCK];
    if (lane == 0) {
        float cosv = dot / (sqrtf(s1) * sqrtf(s2));
        float dist = 0.5f * (1.0f - cosv);
        int t = target[row];
        float loss;
        if (t != 0) {
            loss = 0.5f * dist;
        } else {
            float h = fmaxf(0.0f, 1.0f - sqrtf(dist + 1e-9f));
            loss = 0.5f * h * h;
        }
        sl[wv] = loss;
    }
    __syncthreads();
    if (threadIdx.x == 0) {
        block_partial[blockIdx.x] = (sl[0] + sl[1]) + (sl[2] + sl[3]);
    }
}

__global__ __launch_bounds__(BLOCK) void reduce_mean(
    const float* __restrict__ block_partial,
    float* __restrict__ out,
    int nPartial, int B) {
    // Single block; deterministic fixed-order reduction of 2048 partials.
    float sum = 0.0f;
    for (int i = threadIdx.x; i < nPartial; i += BLOCK) sum += block_partial[i];

    #pragma unroll
    for (int off = 32; off > 0; off >>= 1) sum += __shfl_down(sum, off, WAVE);

    __shared__ float smem[WAVES_PER_BLOCK];
    const int lane = threadIdx.x & 63;
    const int wv   = threadIdx.x >> 6;
    if (lane == 0) smem[wv] = sum;
    __syncthreads();
    if (threadIdx.x == 0) {
        float tot = 0.0f;
        #pragma unroll
        for (int w = 0; w < WAVES_PER_BLOCK; ++w) tot += smem[w];
        out[0] = tot / (float)B;
    }
}

extern "C" void kernel_launch(void* const* d_in, const int* in_sizes, int n_in,
                              void* d_out, int out_size, void* d_ws, size_t ws_size,
                              hipStream_t stream) {
    const float* o1 = (const float*)d_in[0];
    const float* o2 = (const float*)d_in[1];
    const int* tgt = (const int*)d_in[2];

    const int B = in_sizes[2];            // 8192
    const int D = in_sizes[0] / B;        // 4096

    float* block_partial = (float*)d_ws;  // grid floats
    float* out = (float*)d_out;

    const int grid = (B + WAVES_PER_BLOCK - 1) / WAVES_PER_BLOCK;  // 2048
    contrastive_row_loss<<<grid, BLOCK, 0, stream>>>(o1, o2, tgt,
                                                     block_partial, B, D);
    reduce_mean<<<1, BLOCK, 0, stream>>>(block_partial, out, grid, B);
}